// Round 6
// baseline (159.169 us; speedup 1.0000x reference)
//
#include <hip/hip_runtime.h>

// x volumes: [256,256,256] fp32. Row (d,h) = 256 floats = 64 float4.
// float4-unit offset: d*16384 + h*64 + lane. float-unit: d*65536 + h*256 + 4*lane.
//
// Grid: 64 htiles (4 h-rows, one per wave) x 127 d-chunks (2 deep) = 8128
// blocks = 32 blocks/CU queued = 4x oversubscription of the 8-resident cap.
// R5 lesson: grid == 1x resident capacity -> time-avg occupancy 33% (dispatch
// imbalance + drain tail); occupancy tracks oversubscription, not static caps.
// Per-wave wins kept from R5: __builtin_amdgcn_sqrtf (single v_sqrt_f32),
// w-edge scalars loaded from global (L1-hit, same lines as the row) instead
// of __shfl (dependent ds_bpermute on critical path), register rolling along d.
// R3 lesson: no __threadfence / fused finalize (per-XCD L2 writeback storm).

__global__ __launch_bounds__(256) void grad_loss_kernel(const float* __restrict__ xf1,
                                                        const float* __restrict__ xf2,
                                                        double* __restrict__ acc) {
    const float4* __restrict__ x1 = (const float4*)xf1;
    const float4* __restrict__ x2 = (const float4*)xf2;

    const int tid   = threadIdx.x;
    const int lane  = tid & 63;
    const int hslot = tid >> 6;
    const int htile = blockIdx.x & 63;
    const int dchk  = blockIdx.x >> 6;      // 0..126

    const int h  = 1 + htile * 4 + hslot;   // 1..256 (mask >254)
    const int d0 = 1 + dchk * 2;            // 1,3,...,253 -> d in {d0, d0+1} ⊆ [1,254]

    // per-voxel w-axis weights (0 = excluded border voxel, 2 = edge-replicated)
    const int wbase = 4 * lane;
    const float ww0 = (wbase + 0 == 0)   ? 0.0f : 1.0f;
    const float ww1 = (wbase + 1 == 1)   ? 2.0f : 1.0f;
    const float ww2 = (wbase + 2 == 254) ? 2.0f : 1.0f;
    const float ww3 = (wbase + 3 == 255) ? 0.0f : 1.0f;

    float val = 0.0f;

    if (h <= 254) {
        const float whf = (h == 1 || h == 254) ? 2.0f : 1.0f;
        const int rowbase = h * 64 + lane;       // float4 units (without d)
        const int frow    = h * 256 + wbase;     // float units (without d)

        // rolling window along d: a = row(d-1), b = row(d)
        float4 a1 = x1[(d0 - 1) * 16384 + rowbase];
        float4 b1 = x1[d0 * 16384 + rowbase];
        float4 a2 = x2[(d0 - 1) * 16384 + rowbase];
        float4 b2 = x2[d0 * 16384 + rowbase];

        #pragma unroll
        for (int i = 0; i < 2; ++i) {
            const int d = d0 + i;
            const int base = d * 16384 + rowbase;
            const int fb   = d * 65536 + frow;

            float4 c1 = x1[base + 16384];
            float4 u1 = x1[base - 64];
            float4 v1 = x1[base + 64];
            float  l1 = xf1[fb - 1];
            float  r1 = xf1[fb + 4];
            float4 c2 = x2[base + 16384];
            float4 u2 = x2[base - 64];
            float4 v2 = x2[base + 64];
            float  l2 = xf2[fb - 1];
            float  r2 = xf2[fb + 4];

            float gw, gd, gh;
            gw = c1.x - a1.x; gd = v1.x - u1.x; gh = b1.y - l1;
            float m10 = __builtin_amdgcn_sqrtf(gw * gw + gd * gd + gh * gh + 1e-6f);
            gw = c1.y - a1.y; gd = v1.y - u1.y; gh = b1.z - b1.x;
            float m11 = __builtin_amdgcn_sqrtf(gw * gw + gd * gd + gh * gh + 1e-6f);
            gw = c1.z - a1.z; gd = v1.z - u1.z; gh = b1.w - b1.y;
            float m12 = __builtin_amdgcn_sqrtf(gw * gw + gd * gd + gh * gh + 1e-6f);
            gw = c1.w - a1.w; gd = v1.w - u1.w; gh = r1 - b1.z;
            float m13 = __builtin_amdgcn_sqrtf(gw * gw + gd * gd + gh * gh + 1e-6f);

            gw = c2.x - a2.x; gd = v2.x - u2.x; gh = b2.y - l2;
            float m20 = __builtin_amdgcn_sqrtf(gw * gw + gd * gd + gh * gh + 1e-6f);
            gw = c2.y - a2.y; gd = v2.y - u2.y; gh = b2.z - b2.x;
            float m21 = __builtin_amdgcn_sqrtf(gw * gw + gd * gd + gh * gh + 1e-6f);
            gw = c2.z - a2.z; gd = v2.z - u2.z; gh = b2.w - b2.y;
            float m22 = __builtin_amdgcn_sqrtf(gw * gw + gd * gd + gh * gh + 1e-6f);
            gw = c2.w - a2.w; gd = v2.w - u2.w; gh = r2 - b2.z;
            float m23 = __builtin_amdgcn_sqrtf(gw * gw + gd * gd + gh * gh + 1e-6f);

            float inner = ww0 * fabsf(m10 - m20)
                        + ww1 * fabsf(m11 - m21)
                        + ww2 * fabsf(m12 - m22)
                        + ww3 * fabsf(m13 - m23);

            const float wdf = (d == 1 || d == 254) ? 2.0f : 1.0f;
            val += wdf * whf * inner;

            a1 = b1; b1 = c1;
            a2 = b2; b2 = c2;
        }
    }

    // wave-64 reduction
    for (int off = 32; off > 0; off >>= 1)
        val += __shfl_down(val, off, 64);

    __shared__ float smem[4];
    const int lid = tid & 63;
    const int wid = tid >> 6;
    if (lid == 0) smem[wid] = val;
    __syncthreads();

    if (wid == 0) {
        float s = (lid < 4) ? smem[lid] : 0.0f;
        s += __shfl_down(s, 2, 64);
        s += __shfl_down(s, 1, 64);
        if (lid == 0)
            atomicAdd(&acc[blockIdx.x & 255], (double)s);   // no fence!
    }
}

__global__ void finalize_kernel(const double* __restrict__ acc, float* __restrict__ out) {
    double v = acc[threadIdx.x];   // 256 threads, one slot each
    for (int off = 32; off > 0; off >>= 1)
        v += __shfl_down(v, off, 64);

    __shared__ double smem[4];
    const int lid = threadIdx.x & 63;
    const int wid = threadIdx.x >> 6;
    if (lid == 0) smem[wid] = v;
    __syncthreads();

    if (threadIdx.x == 0) {
        double s = smem[0] + smem[1] + smem[2] + smem[3];
        out[0] = (float)(s / 16777216.0);   // mean over 256^3
    }
}

extern "C" void kernel_launch(void* const* d_in, const int* in_sizes, int n_in,
                              void* d_out, int out_size, void* d_ws, size_t ws_size,
                              hipStream_t stream) {
    const float* x1 = (const float*)d_in[0];
    const float* x2 = (const float*)d_in[1];
    float* out = (float*)d_out;
    double* acc = (double*)d_ws;   // 256 doubles = 2 KiB scratch

    hipMemsetAsync(d_ws, 0, 256 * sizeof(double), stream);
    grad_loss_kernel<<<64 * 127, 256, 0, stream>>>(x1, x2, acc);
    finalize_kernel<<<1, 256, 0, stream>>>(acc, out);
}

// Round 7
// 147.063 us; speedup vs baseline: 1.0823x; 1.0823x over previous
//
#include <hip/hip_runtime.h>

// x volumes: [256,256,256] fp32. Row (d,h) = 256 floats = 64 float4.
// float4-unit offset: d*16384 + h*64 + lane.
//
// 3-axis stencil decomposition: registers roll the d-axis (a/b/c planes of the
// own row), LDS holds the h-axis (block = 4 waves = 4 computed h-rows + 2 halo
// rows staged per d-plane), __shfl handles the w-axis. Depth-2 pipeline: step
// computing depth d prefetches plane d+2 — compute reads only regs + LDS[cur],
// never this step's in-flight loads.
// R4-R6 lesson: 10 VMEM/wave-step (6 f4 rows + 4 sparse 16B-stride edge loads
// ~17 L1 lines each) saturated L1/TA service; all occupancy/ILP mixes stuck at
// 52-56us. This drops VMEM to 3 f4 loads/wave-step and kills the sparse loads.
// R3 lesson: no __threadfence / fused finalize (per-XCD L2 writeback storm).
//
// Grid: 64 htiles x 64 d-chunks (4 deep) = 4096 blocks x 256 thr, 24 KB LDS.

#define D_CHUNK 4

__global__ __launch_bounds__(256) void grad_loss_kernel(const float* __restrict__ xf1,
                                                        const float* __restrict__ xf2,
                                                        double* __restrict__ acc) {
    const float4* __restrict__ x1 = (const float4*)xf1;
    const float4* __restrict__ x2 = (const float4*)xf2;

    // [buf][input][row-slot][lane]; slot s holds row h0-1+s. 24 KB.
    __shared__ float4 plane[2][2][6][64];

    const int tid   = threadIdx.x;
    const int lane  = tid & 63;
    const int wid   = tid >> 6;         // 0..3
    const int htile = blockIdx.x & 63;  // 0..63
    const int dchk  = blockIdx.x >> 6;  // 0..63

    const int h0 = 1 + htile * 4;       // computed rows h0..h0+3 (tail rows >254 dead)
    const int d0 = 1 + dchk * D_CHUNK;  // computed depths d0..d0+3 (tail >254 dead)

    const int  h    = h0 + wid;
    const bool live = (h <= 254);
    const int  hrow = (h <= 255) ? h : 255;       // clamped row for loads

    // halo duty: wave0 -> (h0-1, x1), wave1 -> (h0-1, x2),
    //            wave2 -> (h0+4, x1), wave3 -> (h0+4, x2)   (rows clamped)
    const int halo_row  = (wid < 2) ? (h0 - 1) : ((h0 + 4 <= 255) ? (h0 + 4) : 255);
    const int halo_slot = (wid < 2) ? 0 : 5;
    const int halo_inp  = wid & 1;
    const float4* __restrict__ halo4 = halo_inp ? x2 : x1;

    const int own_f4  = hrow * 64 + lane;
    const int halo_f4 = halo_row * 64 + lane;

    // per-voxel w-axis weights (0 = excluded border, 2 = edge-replicated)
    const float ww0 = (lane == 0)  ? 0.0f : 1.0f;   // w = 4*lane   (w==0)
    const float ww1 = (lane == 0)  ? 2.0f : 1.0f;   // w = 4*lane+1 (w==1)
    const float ww2 = (lane == 63) ? 2.0f : 1.0f;   // w = 4*lane+2 (w==254)
    const float ww3 = (lane == 63) ? 0.0f : 1.0f;   // w = 4*lane+3 (w==255)
    const float whf = (h == 1 || h == 254) ? 2.0f : 1.0f;

    // ---- prologue: a=plane(d0-1) own, b=plane(d0) own, LDS[0]=plane d0,
    //                c=plane(d0+1) own + halo reg (staged into LDS next step)
    float4 a1 = x1[(d0 - 1) * 16384 + own_f4];
    float4 a2 = x2[(d0 - 1) * 16384 + own_f4];
    float4 b1 = x1[d0 * 16384 + own_f4];
    float4 b2 = x2[d0 * 16384 + own_f4];
    float4 hb = halo4[d0 * 16384 + halo_f4];
    float4 c1 = x1[(d0 + 1) * 16384 + own_f4];     // d0+1 <= 254 always
    float4 c2 = x2[(d0 + 1) * 16384 + own_f4];
    float4 hc = halo4[(d0 + 1) * 16384 + halo_f4];

    plane[0][0][wid + 1][lane] = b1;
    plane[0][1][wid + 1][lane] = b2;
    plane[0][halo_inp][halo_slot][lane] = hb;
    __syncthreads();

    float val = 0.0f;

    #pragma unroll
    for (int i = 0; i < D_CHUNK; ++i) {
        const int d   = d0 + i;
        const int cur = i & 1;
        const int nxt = cur ^ 1;
        const int dn  = (d + 2 <= 255) ? (d + 2) : 255;   // prefetch depth (clamped tail)

        // prefetch plane d+2 (consumed next iteration) — decoupled from compute
        float4 n1 = x1[dn * 16384 + own_f4];
        float4 n2 = x2[dn * 16384 + own_f4];
        float4 hn = halo4[dn * 16384 + halo_f4];

        // stage plane d+1 (already in regs) into LDS[nxt]
        plane[nxt][0][wid + 1][lane] = c1;
        plane[nxt][1][wid + 1][lane] = c2;
        plane[nxt][halo_inp][halo_slot][lane] = hc;

        // compute depth d from LDS[cur] + a/b/c regs (no wait on this step's loads)
        if (live && d <= 254) {
            float4 u1 = plane[cur][0][wid][lane];       // row h-1
            float4 v1 = plane[cur][0][wid + 2][lane];   // row h+1
            float4 u2 = plane[cur][1][wid][lane];
            float4 v2 = plane[cur][1][wid + 2][lane];

            float l1 = __shfl_up(b1.w, 1, 64);          // garbage on lane0 -> ww0=0
            float r1 = __shfl_down(b1.x, 1, 64);        // garbage on lane63 -> ww3=0
            float l2 = __shfl_up(b2.w, 1, 64);
            float r2 = __shfl_down(b2.x, 1, 64);

            float gw, gd, gh;
            gw = c1.x - a1.x; gd = v1.x - u1.x; gh = b1.y - l1;
            float m10 = __builtin_amdgcn_sqrtf(gw * gw + gd * gd + gh * gh + 1e-6f);
            gw = c1.y - a1.y; gd = v1.y - u1.y; gh = b1.z - b1.x;
            float m11 = __builtin_amdgcn_sqrtf(gw * gw + gd * gd + gh * gh + 1e-6f);
            gw = c1.z - a1.z; gd = v1.z - u1.z; gh = b1.w - b1.y;
            float m12 = __builtin_amdgcn_sqrtf(gw * gw + gd * gd + gh * gh + 1e-6f);
            gw = c1.w - a1.w; gd = v1.w - u1.w; gh = r1 - b1.z;
            float m13 = __builtin_amdgcn_sqrtf(gw * gw + gd * gd + gh * gh + 1e-6f);

            gw = c2.x - a2.x; gd = v2.x - u2.x; gh = b2.y - l2;
            float m20 = __builtin_amdgcn_sqrtf(gw * gw + gd * gd + gh * gh + 1e-6f);
            gw = c2.y - a2.y; gd = v2.y - u2.y; gh = b2.z - b2.x;
            float m21 = __builtin_amdgcn_sqrtf(gw * gw + gd * gd + gh * gh + 1e-6f);
            gw = c2.z - a2.z; gd = v2.z - u2.z; gh = b2.w - b2.y;
            float m22 = __builtin_amdgcn_sqrtf(gw * gw + gd * gd + gh * gh + 1e-6f);
            gw = c2.w - a2.w; gd = v2.w - u2.w; gh = r2 - b2.z;
            float m23 = __builtin_amdgcn_sqrtf(gw * gw + gd * gd + gh * gh + 1e-6f);

            float inner = ww0 * fabsf(m10 - m20)
                        + ww1 * fabsf(m11 - m21)
                        + ww2 * fabsf(m12 - m22)
                        + ww3 * fabsf(m13 - m23);

            const float wdf = (d == 1 || d == 254) ? 2.0f : 1.0f;
            val += wdf * whf * inner;
        }

        a1 = b1; b1 = c1; c1 = n1;
        a2 = b2; b2 = c2; c2 = n2;
        hc = hn;
        __syncthreads();   // plane[nxt] writes visible; plane[cur] reads done
    }

    // wave-64 reduction
    for (int off = 32; off > 0; off >>= 1)
        val += __shfl_down(val, off, 64);

    __shared__ float smem[4];
    if (lane == 0) smem[wid] = val;
    __syncthreads();

    if (wid == 0) {
        float s = (lane < 4) ? smem[lane] : 0.0f;
        s += __shfl_down(s, 2, 64);
        s += __shfl_down(s, 1, 64);
        if (lane == 0)
            atomicAdd(&acc[blockIdx.x & 255], (double)s);   // no fence!
    }
}

__global__ void finalize_kernel(const double* __restrict__ acc, float* __restrict__ out) {
    double v = acc[threadIdx.x];   // 256 threads, one slot each
    for (int off = 32; off > 0; off >>= 1)
        v += __shfl_down(v, off, 64);

    __shared__ double smem[4];
    const int lid = threadIdx.x & 63;
    const int wid = threadIdx.x >> 6;
    if (lid == 0) smem[wid] = v;
    __syncthreads();

    if (threadIdx.x == 0) {
        double s = smem[0] + smem[1] + smem[2] + smem[3];
        out[0] = (float)(s / 16777216.0);   // mean over 256^3
    }
}

extern "C" void kernel_launch(void* const* d_in, const int* in_sizes, int n_in,
                              void* d_out, int out_size, void* d_ws, size_t ws_size,
                              hipStream_t stream) {
    const float* x1 = (const float*)d_in[0];
    const float* x2 = (const float*)d_in[1];
    float* out = (float*)d_out;
    double* acc = (double*)d_ws;   // 256 doubles = 2 KiB scratch

    hipMemsetAsync(d_ws, 0, 256 * sizeof(double), stream);
    grad_loss_kernel<<<64 * 64, 256, 0, stream>>>(x1, x2, acc);
    finalize_kernel<<<1, 256, 0, stream>>>(acc, out);
}